// Round 16
// baseline (310.720 us; speedup 1.0000x reference)
//
#include <hip/hip_runtime.h>

#define BB 8
#define LL 512
#define HH 8
#define BIGV (1e9f)

typedef unsigned short u16;
typedef __attribute__((ext_vector_type(8))) short bf16x8;
typedef __attribute__((ext_vector_type(4))) short s16x4;
typedef __attribute__((ext_vector_type(4))) float f32x4;

#define MFMA(a,b,c) __builtin_amdgcn_mfma_f32_16x16x32_bf16(a,b,c,0,0,0)

__device__ __forceinline__ u16 f2b(float f){
  unsigned u = __float_as_uint(f);
  u = (u + 0x7fffu + ((u>>16)&1u)) >> 16;
  return (u16)u;
}
__device__ __forceinline__ float b2f(u16 s){ return __uint_as_float(((unsigned)s)<<16); }
__device__ __forceinline__ bf16x8 ldb8(const u16* p){ return *(const bf16x8*)p; }

__device__ __forceinline__ float g16_sum(float v){
  v += __shfl_xor(v,1,64); v += __shfl_xor(v,2,64);
  v += __shfl_xor(v,4,64); v += __shfl_xor(v,8,64);
  return v;
}

// ---- tables: T4t[c][b][a], Tt2[c][a][b], Gt[a][j], Gt2[j][a] ----
__global__ void kp_prep(const float* __restrict__ T, const float* __restrict__ gw,
                        u16* __restrict__ T4t, u16* __restrict__ Tt2,
                        u16* __restrict__ Gt, u16* __restrict__ Gt2){
  int idx = blockIdx.x*256 + threadIdx.x;   // < 32768
  { int c=idx>>12, b=(idx>>6)&63, a=idx&63; T4t[idx] = f2b(T[(a*64+b)*8+c]); }
  { int c=idx>>12, a=(idx>>6)&63, b=idx&63; Tt2[idx] = f2b(T[(a*64+b)*8+c]); }
  if(idx < 4096){
    int a=idx>>6, j=idx&63;
    Gt[idx]  = f2b(gw[j*64+a]);   // Gt[a][j]
    Gt2[idx] = f2b(gw[idx]);      // Gt2[j][a]
  }
}

// ---- kCA: fused [new_qz] + [row softmax in-register] + [P2/Mg MFMA] ----
__global__ __launch_bounds__(256) void kCA(const float* __restrict__ x, const int* __restrict__ mask,
      const u16* __restrict__ miP2, const u16* __restrict__ mjP, const float* __restrict__ MgF_in,
      float* __restrict__ unary, float* __restrict__ mf,
      const u16* __restrict__ Gt2, const u16* __restrict__ Gt,
      u16* __restrict__ qzb, float* __restrict__ MgF_out, float* __restrict__ out, int mode){
  __shared__ u16 qlds[16*72];
  __shared__ u16 P2s[16*72];
  __shared__ float red2[16*4];
  int bid = blockIdx.x; int z = bid & 7, itile = bid >> 3;   // z-affine for XCD L2
  int t = threadIdx.x, lane = t&63, w = t>>6, l15 = lane&15, lhi = lane>>4;
  int rbase = z*LL + itile*16;
  {
    int row16 = t>>4, c4 = t&15;
    int rg = rbase + row16;
    int rloc = itile*16 + row16;
    float v[4]; float mk;
    if(mode == 0){
      mk = (mask[rg] != 0) ? 1.f : 0.f;
      if(c4 == 0) mf[rg] = mk;
      int pos = rg & (LL-1);
      #pragma unroll
      for(int k=0;k<4;k++){
        int d = c4*4 + k;
        float div = __expf(-(float)(d & ~1) * 0.14391156962f);  // ln(10000)/64
        float arg = (float)pos * div;
        float pe = (d & 1) ? cosf(arg) : sinf(arg);
        v[k] = (x[(size_t)rg*64 + d] + pe) * mk;
      }
      *(f32x4*)&unary[(size_t)rg*64 + c4*4] = (f32x4){v[0],v[1],v[2],v[3]};
    } else {
      mk = mf[rg];
      f32x4 acc = *(const f32x4*)&MgF_in[(size_t)rg*64 + c4*4];
      #pragma unroll
      for(int hh=0;hh<2;hh++)
        #pragma unroll
        for(int c=0;c<8;c++){
          s16x4 vv = *(const s16x4*)&miP2[(((size_t)(hh*8+z))*LL + rloc)*512 + c*64 + c4*4];
          acc[0]+=b2f((u16)vv[0]); acc[1]+=b2f((u16)vv[1]);
          acc[2]+=b2f((u16)vv[2]); acc[3]+=b2f((u16)vv[3]);
        }
      #pragma unroll
      for(int s=0;s<4;s++)
        #pragma unroll
        for(int c=0;c<8;c++){
          s16x4 vv = *(const s16x4*)&mjP[(((size_t)(s*8+z))*LL + rloc)*512 + c*64 + c4*4];
          acc[0]+=b2f((u16)vv[0]); acc[1]+=b2f((u16)vv[1]);
          acc[2]+=b2f((u16)vv[2]); acc[3]+=b2f((u16)vv[3]);
        }
      f32x4 u0 = *(const f32x4*)&unary[(size_t)rg*64 + c4*4];
      #pragma unroll
      for(int k=0;k<4;k++) v[k] = (u0[k] + acc[k]) * mk;
    }
    if(mode == 2){
      *(f32x4*)&out[(size_t)rg*64 + c4*4] = (f32x4){v[0],v[1],v[2],v[3]};
      return;   // uniform across block: no barrier reached
    }
    // in-register row softmax: 16 lanes per row (group = c4)
    float mx = fmaxf(fmaxf(v[0],v[1]), fmaxf(v[2],v[3]));
    mx = fmaxf(mx, __shfl_xor(mx,1,64));
    mx = fmaxf(mx, __shfl_xor(mx,2,64));
    mx = fmaxf(mx, __shfl_xor(mx,4,64));
    mx = fmaxf(mx, __shfl_xor(mx,8,64));
    float s = 0.f;
    #pragma unroll
    for(int k=0;k<4;k++){ v[k] = __expf(v[k]-mx); s += v[k]; }
    s += __shfl_xor(s,1,64); s += __shfl_xor(s,2,64);
    s += __shfl_xor(s,4,64); s += __shfl_xor(s,8,64);
    float iv = mk / s;
    s16x4 q4 = { (short)f2b(v[0]*iv), (short)f2b(v[1]*iv),
                 (short)f2b(v[2]*iv), (short)f2b(v[3]*iv) };
    *(s16x4*)&qzb[(size_t)rg*64 + c4*4] = q4;
    *(s16x4*)&qlds[row16*72 + c4*4] = q4;
  }
  __syncthreads();
  // ---- P2 = rowsoftmax(qz @ gw^T), one 16x16 quadrant per wave (fixed-max exp) ----
  float fv[4];
  {
    bf16x8 a0 = ldb8(&qlds[l15*72 + lhi*8]);
    bf16x8 a1 = ldb8(&qlds[l15*72 + lhi*8 + 32]);
    const u16* Br = Gt2 + (size_t)(w*16 + l15)*64 + lhi*8;
    f32x4 acc = {0.f,0.f,0.f,0.f};
    acc = MFMA(a0, ldb8(Br), acc);
    acc = MFMA(a1, ldb8(Br+32), acc);
    #pragma unroll
    for(int jj=0;jj<4;jj++){
      float e = __expf(acc[jj]);
      fv[jj] = e;
      float p = g16_sum(e);
      if(l15==0) red2[(lhi*4+jj)*4 + w] = p;
    }
  }
  __syncthreads();
  #pragma unroll
  for(int jj=0;jj<4;jj++){
    int r = lhi*4+jj;
    float s = red2[r*4+0]+red2[r*4+1]+red2[r*4+2]+red2[r*4+3];
    float iv = 1.f/s;
    P2s[r*72 + w*16 + l15] = f2b(fv[jj]*iv);
  }
  __syncthreads();
  // ---- Mg[i,a] = sum_j P2[i,j] gw[j,a]; a-quadrant per wave ----
  {
    bf16x8 a0 = ldb8(&P2s[l15*72 + lhi*8]);
    bf16x8 a1 = ldb8(&P2s[l15*72 + lhi*8 + 32]);
    const u16* Br = Gt + (size_t)(w*16 + l15)*64 + lhi*8;
    f32x4 acc = {0.f,0.f,0.f,0.f};
    acc = MFMA(a0, ldb8(Br), acc);
    acc = MFMA(a1, ldb8(Br+32), acc);
    #pragma unroll
    for(int jj=0;jj<4;jj++)
      MgF_out[((size_t)rbase + lhi*4 + jj)*64 + w*16 + l15] = acc[jj];
  }
}

// ---- k2: per (z,c,itile): t1[i][b], t1t[b][i], t2t[a][j] — LDS-staged stores ----
__global__ __launch_bounds__(256) void k2(const u16* __restrict__ qzb,
      const u16* __restrict__ T4t, const u16* __restrict__ Tt2,
      u16* __restrict__ t1b, u16* __restrict__ t1t, u16* __restrict__ t2t){
  __shared__ u16 s1[64*72];
  __shared__ u16 s2[64*72];
  __shared__ u16 s3[64*72];
  int bid = blockIdx.x; int z = bid&7, c = (bid>>3)&7, itile = bid>>6;
  int zc = z*8 + c;
  int t = threadIdx.x, lane = t&63, w = t>>6, l15 = lane&15, lhi = lane>>4;
  int i0 = itile*64;
  const u16* qA = qzb + ((size_t)z*LL + i0 + w*16 + l15)*64 + lhi*8;
  bf16x8 qa0 = ldb8(qA), qa1 = ldb8(qA+32);
  const u16* tA = T4t + c*4096 + (w*16 + l15)*64 + lhi*8;
  bf16x8 ta0 = ldb8(tA), ta1 = ldb8(tA+32);
  const u16* uA = Tt2 + c*4096 + (w*16 + l15)*64 + lhi*8;
  bf16x8 ua0 = ldb8(uA), ua1 = ldb8(uA+32);
  #pragma unroll
  for(int nt=0;nt<4;nt++){
    {
      const u16* Br = T4t + c*4096 + (nt*16 + l15)*64 + lhi*8;
      f32x4 acc = {0.f,0.f,0.f,0.f};
      acc = MFMA(qa0, ldb8(Br), acc);
      acc = MFMA(qa1, ldb8(Br+32), acc);
      #pragma unroll
      for(int jj=0;jj<4;jj++)
        s1[(w*16 + lhi*4 + jj)*72 + nt*16 + l15] = f2b(acc[jj]);
    }
    const u16* Br = qzb + ((size_t)z*LL + i0 + nt*16 + l15)*64 + lhi*8;
    bf16x8 qb0 = ldb8(Br), qb1 = ldb8(Br+32);
    {
      f32x4 acc = {0.f,0.f,0.f,0.f};
      acc = MFMA(ta0, qb0, acc);
      acc = MFMA(ta1, qb1, acc);
      #pragma unroll
      for(int jj=0;jj<4;jj++)
        s2[(w*16 + lhi*4 + jj)*72 + nt*16 + l15] = f2b(acc[jj]);
    }
    {
      f32x4 acc = {0.f,0.f,0.f,0.f};
      acc = MFMA(ua0, qb0, acc);
      acc = MFMA(ua1, qb1, acc);
      #pragma unroll
      for(int jj=0;jj<4;jj++)
        s3[(w*16 + lhi*4 + jj)*72 + nt*16 + l15] = f2b(acc[jj]);
    }
  }
  __syncthreads();
  #pragma unroll
  for(int p=0;p<2;p++){
    int r = p*32 + (t>>3), ch = t&7;
    *(bf16x8*)&t1b[((size_t)zc*LL + i0 + r)*64 + ch*8]   = *(const bf16x8*)&s1[r*72 + ch*8];
    *(bf16x8*)&t1t[((size_t)zc*64 + r)*LL + i0 + ch*8]   = *(const bf16x8*)&s2[r*72 + ch*8];
    *(bf16x8*)&t2t[((size_t)zc*64 + r)*LL + i0 + ch*8]   = *(const bf16x8*)&s3[r*72 + ch*8];
  }
}

// ---- kF: j-half split for 2 blocks/CU. grid (z,c,it<4,h<2); 16 waves.
// Full-j S/exp/row-sums duplicated across the h-pair (MFMA is 5% util — free);
// LDS holds only h-half of t2t/Pp -> 80128 B <= 81920 -> 2 co-resident blocks.
// In-half waves: PpT+mj (disjoint mjP j-rows). Out-half waves: mi full-K=256
// -> miP2[h] partials (summed in kCA). Register profile identical to round 15.
__global__ __launch_bounds__(1024) void kF(const u16* __restrict__ t1b, const u16* __restrict__ qzb,
        const u16* __restrict__ t1t, const u16* __restrict__ t2t, const float* __restrict__ mf,
        u16* __restrict__ miP2, u16* __restrict__ mjP){
  extern __shared__ char smem[];
  u16*   t2sh = (u16*)smem;                    // [64][264]  33792 B (h-half of t2t[zc])
  u16*   Pph  = (u16*)(smem + 33792);          // [32][264]  16896 B (unnorm exp, h-half)
  u16*   PpT  = (u16*)(smem + 50688);          // [8w][32][40] 20480 B (wave-local, in-half)
  float* redS2= (float*)(smem + 71168);        // [2][32]      256 B (parity row-sums)
  float* stgf = (float*)(smem + 71424);        // [32][68] f32 8704 B  (end 80128)
  u16*   stg  = (u16*)smem;                    // [256][72] dump 36864 B (reuses t2sh+Pph)
  int bid = blockIdx.x;
  int z = bid&7, c = (bid>>3)&7, it = (bid>>6)&3, h = bid>>8;
  int zc = z*8 + c;
  int t = threadIdx.x, lane = t&63, w = t>>6, l15 = lane&15, lhi = lane>>4;
  int jc0 = w*32;                               // wave's global j-slice
  int inh = ((w>>3) == h);                      // j-slice inside this block's half
  int win = w & 7;                              // index within octet
  int wr2 = (win>>2)&1, wc2 = win&3;            // mi tile role (out-half waves)
  // zero parity sum buffers; barrier before any global load (empty drain)
  if(t < 64) redS2[t] = 0.f;
  __syncthreads();
  // ---- stage h-half of t2t[zc] -> t2sh ----
  #pragma unroll
  for(int m=0;m<2;m++){
    int e = (m*1024 + t)*8;
    int a = e >> 8, j = e & 255;
    *(bf16x8*)&t2sh[a*264 + j] = ldb8(t2t + ((size_t)zc*64 + a)*LL + h*256 + j);
  }
  float mfj[2];
  mfj[0] = mf[z*LL + jc0 + l15];
  mfj[1] = mf[z*LL + jc0 + 16 + l15];
  f32x4 mj[2][4];
  #pragma unroll
  for(int jt=0;jt<2;jt++)
    #pragma unroll
    for(int bt=0;bt<4;bt++) mj[jt][bt] = (f32x4){0.f,0.f,0.f,0.f};
  u16* PpTw = PpT + win*32*40;                  // wave-local transpose buffer

  for(int ip=0; ip<4; ++ip){
    int i0g = it*128 + ip*32;
    int par = ip & 1;
    // ---- S panel: full j (duplicated across h-pair), wave's 32 cols ----
    f32x4 S[2][2];
    #pragma unroll
    for(int rt=0;rt<2;rt++){ S[rt][0] = (f32x4){0,0,0,0}; S[rt][1] = (f32x4){0,0,0,0}; }
    #pragma unroll
    for(int rt=0;rt<2;rt++){
      const u16* Ar = t1b + ((size_t)zc*LL + i0g + rt*16 + l15)*64 + lhi*8;
      bf16x8 a0 = ldb8(Ar), a1 = ldb8(Ar+32);
      #pragma unroll
      for(int ct=0;ct<2;ct++){
        const u16* Br = qzb + ((size_t)z*LL + jc0 + ct*16 + l15)*64 + lhi*8;
        S[rt][ct] = MFMA(a0, ldb8(Br), S[rt][ct]);
        S[rt][ct] = MFMA(a1, ldb8(Br+32), S[rt][ct]);
      }
    }
    // ---- mask/diag/exp (fixed max), atomic full-j row-sums; Pph if in-half ----
    #pragma unroll
    for(int rt=0;rt<2;rt++)
      #pragma unroll
      for(int jj=0;jj<4;jj++){
        int rloc = rt*16 + lhi*4 + jj;
        int irow = i0g + rloc;
        float mfi = mf[z*LL + irow];
        float ps = 0.f;
        #pragma unroll
        for(int ct=0;ct<2;ct++){
          int jcol = jc0 + ct*16 + l15;
          float v = S[rt][ct][jj] - ((irow==jcol)?BIGV:0.f);
          float e = mfi * mfj[ct] * __expf(v);
          S[rt][ct][jj] = e; ps += e;
          if(inh) Pph[rloc*264 + win*32 + ct*16 + l15] = f2b(e);
        }
        ps = g16_sum(ps);
        if(l15 == 0) atomicAdd(&redS2[par*32 + rloc], ps);   // ds_add_f32
      }
    __syncthreads();                            // B1: Pph + redS2[par] (t2sh on ip=0)
    if(t < 32) redS2[(par^1)*32 + t] = 0.f;     // zero other parity for next panel
    float ivv[2][4];
    #pragma unroll
    for(int rt=0;rt<2;rt++)
      #pragma unroll
      for(int jj=0;jj<4;jj++){
        float s = redS2[par*32 + rt*16 + lhi*4 + jj];
        ivv[rt][jj] = s > 0.f ? 1.f/s : 0.f;
      }
    if(inh){
      // ---- normalized wave-local PpT; mj accumulate (A own PpT, B t1t) ----
      #pragma unroll
      for(int rt=0;rt<2;rt++)
        #pragma unroll
        for(int ct=0;ct<2;ct++){
          s16x4 v4 = { (short)f2b(S[rt][ct][0]*ivv[rt][0]), (short)f2b(S[rt][ct][1]*ivv[rt][1]),
                       (short)f2b(S[rt][ct][2]*ivv[rt][2]), (short)f2b(S[rt][ct][3]*ivv[rt][3]) };
          *(s16x4*)&PpTw[(ct*16 + l15)*40 + rt*16 + lhi*4] = v4;
        }
      bf16x8 av[2];
      #pragma unroll
      for(int jt=0;jt<2;jt++)
        av[jt] = ldb8(PpTw + (jt*16 + l15)*40 + lhi*8);
      #pragma unroll
      for(int bt=0;bt<4;bt++){
        bf16x8 b = ldb8(t1t + ((size_t)zc*64 + bt*16 + l15)*LL + i0g + lhi*8);
        #pragma unroll
        for(int jt=0;jt<2;jt++) mj[jt][bt] = MFMA(av[jt], b, mj[jt][bt]);
      }
    } else {
      // ---- mi: one 16x16 tile per wave, full block-K=256; iv post-scale ----
      f32x4 mia = {0.f,0.f,0.f,0.f};
      const u16* Ab = Pph + (wr2*16 + l15)*264 + lhi*8;
      const u16* Bb = t2sh + (wc2*16 + l15)*264 + lhi*8;
      #pragma unroll
      for(int ks=0;ks<8;ks++)
        mia = MFMA(ldb8(Ab + ks*32), ldb8(Bb + ks*32), mia);
      #pragma unroll
      for(int jj=0;jj<4;jj++)
        stgf[(wr2*16 + lhi*4 + jj)*68 + wc2*16 + l15] = mia[jj]*ivv[wr2][jj];
    }
    __syncthreads();                            // B2: stgf ready; Pph/t2sh reads done
    // ---- mi half-store: 8B coalesced to miP2[h] ----
    if(t < 512){
      int r = t>>4, cc = t&15;
      f32x4 v0 = *(const f32x4*)&stgf[r*68 + cc*4];
      s16x4 o = { (short)f2b(v0[0]), (short)f2b(v0[1]),
                  (short)f2b(v0[2]), (short)f2b(v0[3]) };
      *(s16x4*)&miP2[(((size_t)(h*8 + z))*LL + i0g + r)*512 + c*64 + cc*4] = o;
    }
  }
  // ---- mj dump: in-half waves stage h-half j-rows, single pass ----
  if(inh){
    #pragma unroll
    for(int jt=0;jt<2;jt++)
      #pragma unroll
      for(int bt=0;bt<4;bt++)
        #pragma unroll
        for(int jj=0;jj<4;jj++)
          stg[(win*32 + jt*16 + lhi*4 + jj)*72 + bt*16 + l15] = f2b(mj[jt][bt][jj]);
  }
  __syncthreads();
  #pragma unroll
  for(int q=0;q<2;q++){
    int e = q*1024 + t;
    int j = e >> 3, ch = e & 7;
    *(bf16x8*)&mjP[(((size_t)(it*8 + z))*LL + h*256 + j)*512 + c*64 + ch*8]
      = *(const bf16x8*)&stg[j*72 + ch*8];
  }
}

extern "C" void kernel_launch(void* const* d_in, const int* in_sizes, int n_in,
                              void* d_out, int out_size, void* d_ws, size_t ws_size,
                              hipStream_t stream) {
  const float* x       = (const float*)d_in[0];
  const int*   mask    = (const int*)d_in[1];
  const float* ternary = (const float*)d_in[2];
  const float* gw      = (const float*)d_in[3];
  float* out = (float*)d_out;

  const size_t NE = (size_t)BB*LL*64;          // 262144
  char* p = (char*)d_ws;
  auto alloc = [&](size_t bytes)->void*{
    void* r = (void*)p; p += (bytes + 255) & ~(size_t)255; return r;
  };
  float* unary   = (float*)alloc(NE*4);
  float* mf      = (float*)alloc((size_t)BB*LL*4);
  u16*   qzb     = (u16*)alloc(NE*2);
  u16*   t1b     = (u16*)alloc((size_t)BB*HH*LL*64*2);   // 4.2 MB
  u16*   t1t     = (u16*)alloc((size_t)BB*HH*LL*64*2);   // 4.2 MB
  u16*   t2t     = (u16*)alloc((size_t)BB*HH*LL*64*2);   // 4.2 MB
  float* MgF     = (float*)alloc(NE*4);                  // 1 MB
  u16*   miP2    = (u16*)alloc((size_t)2*BB*LL*512*2);   // 8.4 MB (2 K-half partials)
  u16*   mjP     = (u16*)alloc((size_t)32*LL*512*2);     // 16.8 MB (4 it-partials)
  u16*   T4t     = (u16*)alloc(32768*2);
  u16*   Tt2     = (u16*)alloc(32768*2);
  u16*   Gt      = (u16*)alloc(4096*2);
  u16*   Gt2     = (u16*)alloc(4096*2);

  const int KF_LDS = 80128;  // t2sh 33792 + Pph 16896 + PpT 20480 + redS2 256 + stgf 8704
  hipFuncSetAttribute(reinterpret_cast<const void*>(kF),
                      hipFuncAttributeMaxDynamicSharedMemorySize, KF_LDS);

  kp_prep<<<128, 256, 0, stream>>>(ternary, gw, T4t, Tt2, Gt, Gt2);
  kCA<<<256, 256, 0, stream>>>(x, mask, miP2, mjP, MgF, unary, mf, Gt2, Gt,
                               qzb, MgF, out, 0);
  for(int it=0; it<4; ++it){
    k2<<<512, 256, 0, stream>>>(qzb, T4t, Tt2, t1b, t1t, t2t);
    kF<<<512, 1024, KF_LDS, stream>>>(t1b, qzb, t1t, t2t, mf, miP2, mjP);
    kCA<<<256, 256, 0, stream>>>(x, mask, miP2, mjP, MgF, unary, mf, Gt2, Gt,
                                 qzb, MgF, out, (it==3) ? 2 : 1);
  }
}

// Round 17
// 218.826 us; speedup vs baseline: 1.4199x; 1.4199x over previous
//
#include <hip/hip_runtime.h>

#define BB 8
#define LL 512
#define HH 8
#define BIGV (1e9f)

typedef unsigned short u16;
typedef __attribute__((ext_vector_type(8))) short bf16x8;
typedef __attribute__((ext_vector_type(4))) short s16x4;
typedef __attribute__((ext_vector_type(4))) float f32x4;

#define MFMA(a,b,c) __builtin_amdgcn_mfma_f32_16x16x32_bf16(a,b,c,0,0,0)

__device__ __forceinline__ u16 f2b(float f){
  unsigned u = __float_as_uint(f);
  u = (u + 0x7fffu + ((u>>16)&1u)) >> 16;
  return (u16)u;
}
__device__ __forceinline__ float b2f(u16 s){ return __uint_as_float(((unsigned)s)<<16); }
__device__ __forceinline__ bf16x8 ldb8(const u16* p){ return *(const bf16x8*)p; }
__device__ __forceinline__ s16x4 ld4nt(const u16* p){ return __builtin_nontemporal_load((const s16x4*)p); }

__device__ __forceinline__ float g16_sum(float v){
  v += __shfl_xor(v,1,64); v += __shfl_xor(v,2,64);
  v += __shfl_xor(v,4,64); v += __shfl_xor(v,8,64);
  return v;
}

// ---- tables: T4t[c][b][a], Tt2[c][a][b], Gt[a][j], Gt2[j][a] ----
__global__ void kp_prep(const float* __restrict__ T, const float* __restrict__ gw,
                        u16* __restrict__ T4t, u16* __restrict__ Tt2,
                        u16* __restrict__ Gt, u16* __restrict__ Gt2){
  int idx = blockIdx.x*256 + threadIdx.x;   // < 32768
  { int c=idx>>12, b=(idx>>6)&63, a=idx&63; T4t[idx] = f2b(T[(a*64+b)*8+c]); }
  { int c=idx>>12, a=(idx>>6)&63, b=idx&63; Tt2[idx] = f2b(T[(a*64+b)*8+c]); }
  if(idx < 4096){
    int a=idx>>6, j=idx&63;
    Gt[idx]  = f2b(gw[j*64+a]);   // Gt[a][j]
    Gt2[idx] = f2b(gw[idx]);      // Gt2[j][a]
  }
}

// ---- kCA: fused [new_qz] + [row softmax in-register] + [P2/Mg MFMA] ----
__global__ __launch_bounds__(256) void kCA(const float* __restrict__ x, const int* __restrict__ mask,
      const u16* __restrict__ miP, const u16* __restrict__ mjP, const float* __restrict__ MgF_in,
      float* __restrict__ unary, float* __restrict__ mf,
      const u16* __restrict__ Gt2, const u16* __restrict__ Gt,
      u16* __restrict__ qzb, float* __restrict__ MgF_out, float* __restrict__ out, int mode){
  __shared__ u16 qlds[16*72];
  __shared__ u16 P2s[16*72];
  __shared__ float red2[16*4];
  int bid = blockIdx.x; int z = bid & 7, itile = bid >> 3;   // z-affine for XCD L2
  int t = threadIdx.x, lane = t&63, w = t>>6, l15 = lane&15, lhi = lane>>4;
  int rbase = z*LL + itile*16;
  {
    int row16 = t>>4, c4 = t&15;
    int rg = rbase + row16;
    float v[4]; float mk;
    if(mode == 0){
      mk = (mask[rg] != 0) ? 1.f : 0.f;
      if(c4 == 0) mf[rg] = mk;
      int pos = rg & (LL-1);
      #pragma unroll
      for(int k=0;k<4;k++){
        int d = c4*4 + k;
        float div = __expf(-(float)(d & ~1) * 0.14391156962f);  // ln(10000)/64
        float arg = (float)pos * div;
        float pe = (d & 1) ? cosf(arg) : sinf(arg);
        v[k] = (x[(size_t)rg*64 + d] + pe) * mk;
      }
      *(f32x4*)&unary[(size_t)rg*64 + c4*4] = (f32x4){v[0],v[1],v[2],v[3]};
    } else {
      mk = mf[rg];
      f32x4 acc = *(const f32x4*)&MgF_in[(size_t)rg*64 + c4*4];
      #pragma unroll
      for(int c=0;c<8;c++){
        s16x4 vv = ld4nt(&miP[(size_t)rg*512 + c*64 + c4*4]);
        acc[0]+=b2f((u16)vv[0]); acc[1]+=b2f((u16)vv[1]);
        acc[2]+=b2f((u16)vv[2]); acc[3]+=b2f((u16)vv[3]);
      }
      #pragma unroll
      for(int s=0;s<4;s++)
        #pragma unroll
        for(int c=0;c<8;c++){
          s16x4 vv = ld4nt(&mjP[(((size_t)(s*8+z))*LL + itile*16 + row16)*512 + c*64 + c4*4]);
          acc[0]+=b2f((u16)vv[0]); acc[1]+=b2f((u16)vv[1]);
          acc[2]+=b2f((u16)vv[2]); acc[3]+=b2f((u16)vv[3]);
        }
      f32x4 u0 = *(const f32x4*)&unary[(size_t)rg*64 + c4*4];
      #pragma unroll
      for(int k=0;k<4;k++) v[k] = (u0[k] + acc[k]) * mk;
    }
    if(mode == 2){
      *(f32x4*)&out[(size_t)rg*64 + c4*4] = (f32x4){v[0],v[1],v[2],v[3]};
      return;   // uniform across block: no barrier reached
    }
    // in-register row softmax: 16 lanes per row (group = c4)
    float mx = fmaxf(fmaxf(v[0],v[1]), fmaxf(v[2],v[3]));
    mx = fmaxf(mx, __shfl_xor(mx,1,64));
    mx = fmaxf(mx, __shfl_xor(mx,2,64));
    mx = fmaxf(mx, __shfl_xor(mx,4,64));
    mx = fmaxf(mx, __shfl_xor(mx,8,64));
    float s = 0.f;
    #pragma unroll
    for(int k=0;k<4;k++){ v[k] = __expf(v[k]-mx); s += v[k]; }
    s += __shfl_xor(s,1,64); s += __shfl_xor(s,2,64);
    s += __shfl_xor(s,4,64); s += __shfl_xor(s,8,64);
    float iv = mk / s;
    s16x4 q4 = { (short)f2b(v[0]*iv), (short)f2b(v[1]*iv),
                 (short)f2b(v[2]*iv), (short)f2b(v[3]*iv) };
    *(s16x4*)&qzb[(size_t)rg*64 + c4*4] = q4;
    *(s16x4*)&qlds[row16*72 + c4*4] = q4;
  }
  __syncthreads();
  // ---- P2 = rowsoftmax(qz @ gw^T), one 16x16 quadrant per wave (fixed-max exp) ----
  float fv[4];
  {
    bf16x8 a0 = ldb8(&qlds[l15*72 + lhi*8]);
    bf16x8 a1 = ldb8(&qlds[l15*72 + lhi*8 + 32]);
    const u16* Br = Gt2 + (size_t)(w*16 + l15)*64 + lhi*8;
    f32x4 acc = {0.f,0.f,0.f,0.f};
    acc = MFMA(a0, ldb8(Br), acc);
    acc = MFMA(a1, ldb8(Br+32), acc);
    #pragma unroll
    for(int jj=0;jj<4;jj++){
      float e = __expf(acc[jj]);
      fv[jj] = e;
      float p = g16_sum(e);
      if(l15==0) red2[(lhi*4+jj)*4 + w] = p;
    }
  }
  __syncthreads();
  #pragma unroll
  for(int jj=0;jj<4;jj++){
    int r = lhi*4+jj;
    float s = red2[r*4+0]+red2[r*4+1]+red2[r*4+2]+red2[r*4+3];
    float iv = 1.f/s;
    P2s[r*72 + w*16 + l15] = f2b(fv[jj]*iv);
  }
  __syncthreads();
  // ---- Mg[i,a] = sum_j P2[i,j] gw[j,a]; a-quadrant per wave ----
  {
    bf16x8 a0 = ldb8(&P2s[l15*72 + lhi*8]);
    bf16x8 a1 = ldb8(&P2s[l15*72 + lhi*8 + 32]);
    const u16* Br = Gt + (size_t)(w*16 + l15)*64 + lhi*8;
    f32x4 acc = {0.f,0.f,0.f,0.f};
    acc = MFMA(a0, ldb8(Br), acc);
    acc = MFMA(a1, ldb8(Br+32), acc);
    #pragma unroll
    for(int jj=0;jj<4;jj++)
      MgF_out[((size_t)rbase + lhi*4 + jj)*64 + w*16 + l15] = acc[jj];
  }
}

// ---- k2: per (z,c,itile): t1[i][b], t1t[b][i], t2t[a][j] — LDS-staged stores ----
__global__ __launch_bounds__(256) void k2(const u16* __restrict__ qzb,
      const u16* __restrict__ T4t, const u16* __restrict__ Tt2,
      u16* __restrict__ t1b, u16* __restrict__ t1t, u16* __restrict__ t2t){
  __shared__ u16 s1[64*72];
  __shared__ u16 s2[64*72];
  __shared__ u16 s3[64*72];
  int bid = blockIdx.x; int z = bid&7, c = (bid>>3)&7, itile = bid>>6;
  int zc = z*8 + c;
  int t = threadIdx.x, lane = t&63, w = t>>6, l15 = lane&15, lhi = lane>>4;
  int i0 = itile*64;
  const u16* qA = qzb + ((size_t)z*LL + i0 + w*16 + l15)*64 + lhi*8;
  bf16x8 qa0 = ldb8(qA), qa1 = ldb8(qA+32);
  const u16* tA = T4t + c*4096 + (w*16 + l15)*64 + lhi*8;
  bf16x8 ta0 = ldb8(tA), ta1 = ldb8(tA+32);
  const u16* uA = Tt2 + c*4096 + (w*16 + l15)*64 + lhi*8;
  bf16x8 ua0 = ldb8(uA), ua1 = ldb8(uA+32);
  #pragma unroll
  for(int nt=0;nt<4;nt++){
    {
      const u16* Br = T4t + c*4096 + (nt*16 + l15)*64 + lhi*8;
      f32x4 acc = {0.f,0.f,0.f,0.f};
      acc = MFMA(qa0, ldb8(Br), acc);
      acc = MFMA(qa1, ldb8(Br+32), acc);
      #pragma unroll
      for(int jj=0;jj<4;jj++)
        s1[(w*16 + lhi*4 + jj)*72 + nt*16 + l15] = f2b(acc[jj]);
    }
    const u16* Br = qzb + ((size_t)z*LL + i0 + nt*16 + l15)*64 + lhi*8;
    bf16x8 qb0 = ldb8(Br), qb1 = ldb8(Br+32);
    {
      f32x4 acc = {0.f,0.f,0.f,0.f};
      acc = MFMA(ta0, qb0, acc);
      acc = MFMA(ta1, qb1, acc);
      #pragma unroll
      for(int jj=0;jj<4;jj++)
        s2[(w*16 + lhi*4 + jj)*72 + nt*16 + l15] = f2b(acc[jj]);
    }
    {
      f32x4 acc = {0.f,0.f,0.f,0.f};
      acc = MFMA(ua0, qb0, acc);
      acc = MFMA(ua1, qb1, acc);
      #pragma unroll
      for(int jj=0;jj<4;jj++)
        s3[(w*16 + lhi*4 + jj)*72 + nt*16 + l15] = f2b(acc[jj]);
    }
  }
  __syncthreads();
  #pragma unroll
  for(int p=0;p<2;p++){
    int r = p*32 + (t>>3), ch = t&7;
    *(bf16x8*)&t1b[((size_t)zc*LL + i0 + r)*64 + ch*8]   = *(const bf16x8*)&s1[r*72 + ch*8];
    *(bf16x8*)&t1t[((size_t)zc*64 + r)*LL + i0 + ch*8]   = *(const bf16x8*)&s2[r*72 + ch*8];
    *(bf16x8*)&t2t[((size_t)zc*64 + r)*LL + i0 + ch*8]   = *(const bf16x8*)&s3[r*72 + ch*8];
  }
}

// ---- kF: round-15 structure (verified 40us): t2s LDS stage + unnorm Pp +
// wave-local PpT + LDS-atomic parity row-sums (2 barriers/panel). ----
__global__ __launch_bounds__(1024) void kF(const u16* __restrict__ t1b, const u16* __restrict__ qzb,
        const u16* __restrict__ t1t, const u16* __restrict__ t2t, const float* __restrict__ mf,
        u16* __restrict__ miP, u16* __restrict__ mjP){
  extern __shared__ char smem[];
  u16*   t2s  = (u16*)smem;                    // [64][520]   66560 B
  u16*   Pp   = (u16*)(smem + 66560);          // [32][520]   33280 B (unnormalized exp)
  u16*   PpT  = (u16*)(smem + 99840);          // [16w][32][40] 40960 B (normalized, wave-local)
  float* redS2= (float*)(smem + 140800);       // [2][32]      256 B (parity row-sums)
  float* stgf = (float*)(smem + 141056);       // [2][32][68] f32 17408 B  (end 158464)
  u16*   stg  = (u16*)smem;                    // [512][72] dump (reuses t2s+Pp, 73728 B)
  int bid = blockIdx.x;
  int z = bid&7, c = (bid>>3)&7, it = bid>>6;   // it < 4
  int zc = z*8 + c;
  int t = threadIdx.x, lane = t&63, w = t>>6, l15 = lane&15, lhi = lane>>4;
  int jc0 = w*32;                               // wave's j-slice
  int h = w>>3, wr = (w>>2)&1, wc = w&3;        // mi role
  if(t < 64) redS2[t] = 0.f;
  __syncthreads();
  #pragma unroll
  for(int m=0;m<4;m++){
    int e = (m*1024 + t)*8;
    int a = e >> 9, j = e & 511;
    *(bf16x8*)&t2s[a*520 + j] = ldb8(t2t + ((size_t)zc*64 + a)*LL + j);
  }
  float mfj[2];
  mfj[0] = mf[z*LL + jc0 + l15];
  mfj[1] = mf[z*LL + jc0 + 16 + l15];
  f32x4 mj[2][4];
  #pragma unroll
  for(int jt=0;jt<2;jt++)
    #pragma unroll
    for(int bt=0;bt<4;bt++) mj[jt][bt] = (f32x4){0.f,0.f,0.f,0.f};
  u16* PpTw = PpT + w*32*40;                    // wave-local transpose buffer

  for(int ip=0; ip<4; ++ip){
    int i0g = it*128 + ip*32;
    int par = ip & 1;
    f32x4 S[2][2];
    #pragma unroll
    for(int rt=0;rt<2;rt++){ S[rt][0] = (f32x4){0,0,0,0}; S[rt][1] = (f32x4){0,0,0,0}; }
    #pragma unroll
    for(int rt=0;rt<2;rt++){
      const u16* Ar = t1b + ((size_t)zc*LL + i0g + rt*16 + l15)*64 + lhi*8;
      bf16x8 a0 = ldb8(Ar), a1 = ldb8(Ar+32);
      #pragma unroll
      for(int ct=0;ct<2;ct++){
        const u16* Br = qzb + ((size_t)z*LL + jc0 + ct*16 + l15)*64 + lhi*8;
        S[rt][ct] = MFMA(a0, ldb8(Br), S[rt][ct]);
        S[rt][ct] = MFMA(a1, ldb8(Br+32), S[rt][ct]);
      }
    }
    #pragma unroll
    for(int rt=0;rt<2;rt++)
      #pragma unroll
      for(int jj=0;jj<4;jj++){
        int rloc = rt*16 + lhi*4 + jj;
        int irow = i0g + rloc;
        float mfi = mf[z*LL + irow];
        float ps = 0.f;
        #pragma unroll
        for(int ct=0;ct<2;ct++){
          int jcol = jc0 + ct*16 + l15;
          float v = S[rt][ct][jj] - ((irow==jcol)?BIGV:0.f);
          float e = mfi * mfj[ct] * __expf(v);
          S[rt][ct][jj] = e; ps += e;
          Pp[rloc*520 + jcol] = f2b(e);        // unnormalized
        }
        ps = g16_sum(ps);
        if(l15 == 0) atomicAdd(&redS2[par*32 + rloc], ps);   // ds_add_f32, no-return
      }
    __syncthreads();                            // B1: Pp + redS2[par] complete (t2s on ip=0)
    if(t < 32) redS2[(par^1)*32 + t] = 0.f;     // zero other parity for next panel
    float ivv[2][4];
    #pragma unroll
    for(int rt=0;rt<2;rt++)
      #pragma unroll
      for(int jj=0;jj<4;jj++){
        float s = redS2[par*32 + rt*16 + lhi*4 + jj];
        ivv[rt][jj] = s > 0.f ? 1.f/s : 0.f;
      }
    #pragma unroll
    for(int rt=0;rt<2;rt++)
      #pragma unroll
      for(int ct=0;ct<2;ct++){
        s16x4 v4 = { (short)f2b(S[rt][ct][0]*ivv[rt][0]), (short)f2b(S[rt][ct][1]*ivv[rt][1]),
                     (short)f2b(S[rt][ct][2]*ivv[rt][2]), (short)f2b(S[rt][ct][3]*ivv[rt][3]) };
        *(s16x4*)&PpTw[(ct*16 + l15)*40 + rt*16 + lhi*4] = v4;
      }
    {
      f32x4 mia = {0.f,0.f,0.f,0.f};
      const u16* Ab = Pp + (wr*16 + l15)*520 + h*256 + lhi*8;
      const u16* Bb = t2s + (wc*16 + l15)*520 + h*256 + lhi*8;
      #pragma unroll
      for(int ks=0;ks<8;ks++)
        mia = MFMA(ldb8(Ab + ks*32), ldb8(Bb + ks*32), mia);
      #pragma unroll
      for(int jj=0;jj<4;jj++)
        stgf[(h*32 + wr*16 + lhi*4 + jj)*68 + wc*16 + l15] = mia[jj]*ivv[wr][jj];
    }
    {
      bf16x8 av[2];
      #pragma unroll
      for(int jt=0;jt<2;jt++)
        av[jt] = ldb8(PpTw + (jt*16 + l15)*40 + lhi*8);
      #pragma unroll
      for(int bt=0;bt<4;bt++){
        bf16x8 b = ldb8(t1t + ((size_t)zc*64 + bt*16 + l15)*LL + i0g + lhi*8);
        #pragma unroll
        for(int jt=0;jt<2;jt++) mj[jt][bt] = MFMA(av[jt], b, mj[jt][bt]);
      }
    }
    __syncthreads();                            // B2: stgf ready; Pp/t2s reads done;
                                                //     orders parity-zero vs next atomics
    if(t < 512){
      int r = t>>4, cc = t&15;
      f32x4 v0 = *(const f32x4*)&stgf[r*68 + cc*4];
      f32x4 v1 = *(const f32x4*)&stgf[(32+r)*68 + cc*4];
      s16x4 o = { (short)f2b(v0[0]+v1[0]), (short)f2b(v0[1]+v1[1]),
                  (short)f2b(v0[2]+v1[2]), (short)f2b(v0[3]+v1[3]) };
      *(s16x4*)&miP[((size_t)z*LL + i0g + r)*512 + c*64 + cc*4] = o;
    }
  }
  // ---- mj dump: single pass, stg[512][72] reuses dead t2s+Pp space ----
  #pragma unroll
  for(int jt=0;jt<2;jt++)
    #pragma unroll
    for(int bt=0;bt<4;bt++)
      #pragma unroll
      for(int jj=0;jj<4;jj++)
        stg[(jc0 + jt*16 + lhi*4 + jj)*72 + bt*16 + l15] = f2b(mj[jt][bt][jj]);
  __syncthreads();
  #pragma unroll
  for(int q=0;q<4;q++){
    int e = q*1024 + t;
    int j = e >> 3, ch = e & 7;
    *(bf16x8*)&mjP[(((size_t)(it*8 + z))*LL + j)*512 + c*64 + ch*8]
      = *(const bf16x8*)&stg[j*72 + ch*8];
  }
}

extern "C" void kernel_launch(void* const* d_in, const int* in_sizes, int n_in,
                              void* d_out, int out_size, void* d_ws, size_t ws_size,
                              hipStream_t stream) {
  const float* x       = (const float*)d_in[0];
  const int*   mask    = (const int*)d_in[1];
  const float* ternary = (const float*)d_in[2];
  const float* gw      = (const float*)d_in[3];
  float* out = (float*)d_out;

  const size_t NE = (size_t)BB*LL*64;          // 262144
  char* p = (char*)d_ws;
  auto alloc = [&](size_t bytes)->void*{
    void* r = (void*)p; p += (bytes + 255) & ~(size_t)255; return r;
  };
  float* unary   = (float*)alloc(NE*4);
  float* mf      = (float*)alloc((size_t)BB*LL*4);
  u16*   qzb     = (u16*)alloc(NE*2);
  u16*   t1b     = (u16*)alloc((size_t)BB*HH*LL*64*2);   // 4.2 MB
  u16*   t1t     = (u16*)alloc((size_t)BB*HH*LL*64*2);   // 4.2 MB
  u16*   t2t     = (u16*)alloc((size_t)BB*HH*LL*64*2);   // 4.2 MB
  float* MgF     = (float*)alloc(NE*4);                  // 1 MB
  u16*   miP     = (u16*)alloc((size_t)BB*LL*512*2);     // 4.2 MB
  u16*   mjP     = (u16*)alloc((size_t)32*LL*512*2);     // 16.8 MB (4 it-partials)
  u16*   T4t     = (u16*)alloc(32768*2);
  u16*   Tt2     = (u16*)alloc(32768*2);
  u16*   Gt      = (u16*)alloc(4096*2);
  u16*   Gt2     = (u16*)alloc(4096*2);

  const int KF_LDS = 158464;  // t2s + Pp + PpT + redS2 + stgf
  hipFuncSetAttribute(reinterpret_cast<const void*>(kF),
                      hipFuncAttributeMaxDynamicSharedMemorySize, KF_LDS);

  kp_prep<<<128, 256, 0, stream>>>(ternary, gw, T4t, Tt2, Gt, Gt2);
  kCA<<<256, 256, 0, stream>>>(x, mask, miP, mjP, MgF, unary, mf, Gt2, Gt,
                               qzb, MgF, out, 0);
  for(int it=0; it<4; ++it){
    k2<<<512, 256, 0, stream>>>(qzb, T4t, Tt2, t1b, t1t, t2t);
    kF<<<256, 1024, KF_LDS, stream>>>(t1b, qzb, t1t, t2t, mf, miP, mjP);
    kCA<<<256, 256, 0, stream>>>(x, mask, miP, mjP, MgF, unary, mf, Gt2, Gt,
                                 qzb, MgF, out, (it==3) ? 2 : 1);
  }
}

// Round 18
// 208.619 us; speedup vs baseline: 1.4894x; 1.0489x over previous
//
#include <hip/hip_runtime.h>

#define BB 8
#define LL 512
#define HH 8
#define BIGV (1e9f)

typedef unsigned short u16;
typedef __attribute__((ext_vector_type(8))) short bf16x8;
typedef __attribute__((ext_vector_type(4))) short s16x4;
typedef __attribute__((ext_vector_type(4))) float f32x4;

#define MFMA(a,b,c) __builtin_amdgcn_mfma_f32_16x16x32_bf16(a,b,c,0,0,0)

__device__ __forceinline__ u16 f2b(float f){
  unsigned u = __float_as_uint(f);
  u = (u + 0x7fffu + ((u>>16)&1u)) >> 16;
  return (u16)u;
}
__device__ __forceinline__ float b2f(u16 s){ return __uint_as_float(((unsigned)s)<<16); }
__device__ __forceinline__ bf16x8 ldb8(const u16* p){ return *(const bf16x8*)p; }
__device__ __forceinline__ s16x4 ld4nt(const u16* p){ return __builtin_nontemporal_load((const s16x4*)p); }

__device__ __forceinline__ float g16_sum(float v){
  v += __shfl_xor(v,1,64); v += __shfl_xor(v,2,64);
  v += __shfl_xor(v,4,64); v += __shfl_xor(v,8,64);
  return v;
}

// ---- tables: T4t[c][b][a], Tt2[c][a][b], Gt[a][j], Gt2[j][a] ----
__global__ void kp_prep(const float* __restrict__ T, const float* __restrict__ gw,
                        u16* __restrict__ T4t, u16* __restrict__ Tt2,
                        u16* __restrict__ Gt, u16* __restrict__ Gt2){
  int idx = blockIdx.x*256 + threadIdx.x;   // < 32768
  { int c=idx>>12, b=(idx>>6)&63, a=idx&63; T4t[idx] = f2b(T[(a*64+b)*8+c]); }
  { int c=idx>>12, a=(idx>>6)&63, b=idx&63; Tt2[idx] = f2b(T[(a*64+b)*8+c]); }
  if(idx < 4096){
    int a=idx>>6, j=idx&63;
    Gt[idx]  = f2b(gw[j*64+a]);   // Gt[a][j]
    Gt2[idx] = f2b(gw[idx]);      // Gt2[j][a]
  }
}

// ---- kCA: fused [new_qz] + [row softmax] + [P2/Mg] + [t1b/t1t/t2t production]
// 512 threads: front (t<256) as before; phase T uses all 8 waves (wave w = channel c)
// to compute the k2 work for this tile's 16 rows — k2 kernel is eliminated.
__global__ __launch_bounds__(512) void kCA(const float* __restrict__ x, const int* __restrict__ mask,
      const u16* __restrict__ miP, const u16* __restrict__ mjP, const float* __restrict__ MgF_in,
      float* __restrict__ unary, float* __restrict__ mf,
      const u16* __restrict__ Gt2, const u16* __restrict__ Gt,
      const u16* __restrict__ T4t, const u16* __restrict__ Tt2,
      u16* __restrict__ qzb, float* __restrict__ MgF_out, float* __restrict__ out,
      u16* __restrict__ t1b, u16* __restrict__ t1t, u16* __restrict__ t2t, int mode){
  __shared__ u16 qlds[16*72];
  __shared__ u16 P2s[16*72];
  __shared__ float red2[16*4];
  int bid = blockIdx.x; int z = bid & 7, itile = bid >> 3;   // z-affine for XCD L2
  int t = threadIdx.x, lane = t&63, w = t>>6, l15 = lane&15, lhi = lane>>4;
  int rbase = z*LL + itile*16;
  if(t < 256){
    int row16 = t>>4, c4 = t&15;
    int rg = rbase + row16;
    float v[4]; float mk;
    if(mode == 0){
      mk = (mask[rg] != 0) ? 1.f : 0.f;
      if(c4 == 0) mf[rg] = mk;
      int pos = rg & (LL-1);
      #pragma unroll
      for(int k=0;k<4;k++){
        int d = c4*4 + k;
        float div = __expf(-(float)(d & ~1) * 0.14391156962f);  // ln(10000)/64
        float arg = (float)pos * div;
        float pe = (d & 1) ? cosf(arg) : sinf(arg);
        v[k] = (x[(size_t)rg*64 + d] + pe) * mk;
      }
      *(f32x4*)&unary[(size_t)rg*64 + c4*4] = (f32x4){v[0],v[1],v[2],v[3]};
    } else {
      mk = mf[rg];
      f32x4 acc = *(const f32x4*)&MgF_in[(size_t)rg*64 + c4*4];
      #pragma unroll
      for(int c=0;c<8;c++){
        s16x4 vv = ld4nt(&miP[(size_t)rg*512 + c*64 + c4*4]);
        acc[0]+=b2f((u16)vv[0]); acc[1]+=b2f((u16)vv[1]);
        acc[2]+=b2f((u16)vv[2]); acc[3]+=b2f((u16)vv[3]);
      }
      #pragma unroll
      for(int s=0;s<4;s++)
        #pragma unroll
        for(int c=0;c<8;c++){
          s16x4 vv = ld4nt(&mjP[(((size_t)(s*8+z))*LL + itile*16 + row16)*512 + c*64 + c4*4]);
          acc[0]+=b2f((u16)vv[0]); acc[1]+=b2f((u16)vv[1]);
          acc[2]+=b2f((u16)vv[2]); acc[3]+=b2f((u16)vv[3]);
        }
      f32x4 u0 = *(const f32x4*)&unary[(size_t)rg*64 + c4*4];
      #pragma unroll
      for(int k=0;k<4;k++) v[k] = (u0[k] + acc[k]) * mk;
    }
    if(mode == 2){
      *(f32x4*)&out[(size_t)rg*64 + c4*4] = (f32x4){v[0],v[1],v[2],v[3]};
    } else {
      // in-register row softmax: 16 lanes per row (group = c4)
      float mx = fmaxf(fmaxf(v[0],v[1]), fmaxf(v[2],v[3]));
      mx = fmaxf(mx, __shfl_xor(mx,1,64));
      mx = fmaxf(mx, __shfl_xor(mx,2,64));
      mx = fmaxf(mx, __shfl_xor(mx,4,64));
      mx = fmaxf(mx, __shfl_xor(mx,8,64));
      float s = 0.f;
      #pragma unroll
      for(int k=0;k<4;k++){ v[k] = __expf(v[k]-mx); s += v[k]; }
      s += __shfl_xor(s,1,64); s += __shfl_xor(s,2,64);
      s += __shfl_xor(s,4,64); s += __shfl_xor(s,8,64);
      float iv = mk / s;
      s16x4 q4 = { (short)f2b(v[0]*iv), (short)f2b(v[1]*iv),
                   (short)f2b(v[2]*iv), (short)f2b(v[3]*iv) };
      *(s16x4*)&qzb[(size_t)rg*64 + c4*4] = q4;
      *(s16x4*)&qlds[row16*72 + c4*4] = q4;
    }
  }
  if(mode == 2) return;                       // uniform: no barrier crossed
  __syncthreads();
  // ---- P2 = rowsoftmax(qz @ gw^T) (waves 0-3; fixed-max exp) ----
  float fv[4];
  if(t < 256){
    bf16x8 a0 = ldb8(&qlds[l15*72 + lhi*8]);
    bf16x8 a1 = ldb8(&qlds[l15*72 + lhi*8 + 32]);
    const u16* Br = Gt2 + (size_t)(w*16 + l15)*64 + lhi*8;
    f32x4 acc = {0.f,0.f,0.f,0.f};
    acc = MFMA(a0, ldb8(Br), acc);
    acc = MFMA(a1, ldb8(Br+32), acc);
    #pragma unroll
    for(int jj=0;jj<4;jj++){
      float e = __expf(acc[jj]);
      fv[jj] = e;
      float p = g16_sum(e);
      if(l15==0) red2[(lhi*4+jj)*4 + w] = p;
    }
  }
  __syncthreads();
  if(t < 256){
    #pragma unroll
    for(int jj=0;jj<4;jj++){
      int r = lhi*4+jj;
      float s = red2[r*4+0]+red2[r*4+1]+red2[r*4+2]+red2[r*4+3];
      float iv = 1.f/s;
      P2s[r*72 + w*16 + l15] = f2b(fv[jj]*iv);
    }
  }
  __syncthreads();
  if(t < 256){
    // ---- Mg[i,a] = sum_j P2[i,j] gw[j,a]; a-quadrant per wave ----
    bf16x8 a0 = ldb8(&P2s[l15*72 + lhi*8]);
    bf16x8 a1 = ldb8(&P2s[l15*72 + lhi*8 + 32]);
    const u16* Br = Gt + (size_t)(w*16 + l15)*64 + lhi*8;
    f32x4 acc = {0.f,0.f,0.f,0.f};
    acc = MFMA(a0, ldb8(Br), acc);
    acc = MFMA(a1, ldb8(Br+32), acc);
    #pragma unroll
    for(int jj=0;jj<4;jj++)
      MgF_out[((size_t)rbase + lhi*4 + jj)*64 + w*16 + l15] = acc[jj];
  }
  // ---- phase T (all 8 waves): t1b/t1t/t2t for this tile's 16 rows; wave w = c ----
  {
    int c = w;
    size_t zc = (size_t)z*8 + c;
    bf16x8 aq0 = ldb8(&qlds[l15*72 + lhi*8]);
    bf16x8 aq1 = ldb8(&qlds[l15*72 + lhi*8 + 32]);
    const u16* T4c = T4t + c*4096;
    const u16* Ttc = Tt2 + c*4096;
    #pragma unroll
    for(int s=0;s<4;s++){
      const u16* Bq = T4c + (s*16 + l15)*64 + lhi*8;
      bf16x8 tb0 = ldb8(Bq), tb1 = ldb8(Bq+32);
      const u16* Uq = Ttc + (s*16 + l15)*64 + lhi*8;
      bf16x8 ub0 = ldb8(Uq), ub1 = ldb8(Uq+32);
      f32x4 d1 = {0.f,0.f,0.f,0.f};               // t1[i][b] (row=i,col=b)
      d1 = MFMA(aq0, tb0, d1);
      d1 = MFMA(aq1, tb1, d1);
      f32x4 d2 = {0.f,0.f,0.f,0.f};               // t1t[b][i] (row=b,col=i)
      d2 = MFMA(tb0, aq0, d2);
      d2 = MFMA(tb1, aq1, d2);
      f32x4 d3 = {0.f,0.f,0.f,0.f};               // t2t[a][j] (row=a,col=j)
      d3 = MFMA(ub0, aq0, d3);
      d3 = MFMA(ub1, aq1, d3);
      #pragma unroll
      for(int jj=0;jj<4;jj++){
        int r4 = lhi*4 + jj;
        t1b[(zc*LL + itile*16 + r4)*64 + s*16 + l15]  = f2b(d1[jj]);
        t1t[(zc*64 + s*16 + r4)*LL + itile*16 + l15]  = f2b(d2[jj]);
        t2t[(zc*64 + s*16 + r4)*LL + itile*16 + l15]  = f2b(d3[jj]);
      }
    }
  }
}

// ---- kF: round-15 structure (verified 40us): t2s LDS stage + unnorm Pp +
// wave-local PpT + LDS-atomic parity row-sums (2 barriers/panel). ----
__global__ __launch_bounds__(1024) void kF(const u16* __restrict__ t1b, const u16* __restrict__ qzb,
        const u16* __restrict__ t1t, const u16* __restrict__ t2t, const float* __restrict__ mf,
        u16* __restrict__ miP, u16* __restrict__ mjP){
  extern __shared__ char smem[];
  u16*   t2s  = (u16*)smem;                    // [64][520]   66560 B
  u16*   Pp   = (u16*)(smem + 66560);          // [32][520]   33280 B (unnormalized exp)
  u16*   PpT  = (u16*)(smem + 99840);          // [16w][32][40] 40960 B (normalized, wave-local)
  float* redS2= (float*)(smem + 140800);       // [2][32]      256 B (parity row-sums)
  float* stgf = (float*)(smem + 141056);       // [2][32][68] f32 17408 B  (end 158464)
  u16*   stg  = (u16*)smem;                    // [512][72] dump (reuses t2s+Pp, 73728 B)
  int bid = blockIdx.x;
  int z = bid&7, c = (bid>>3)&7, it = bid>>6;   // it < 4
  int zc = z*8 + c;
  int t = threadIdx.x, lane = t&63, w = t>>6, l15 = lane&15, lhi = lane>>4;
  int jc0 = w*32;                               // wave's j-slice
  int h = w>>3, wr = (w>>2)&1, wc = w&3;        // mi role
  if(t < 64) redS2[t] = 0.f;
  __syncthreads();
  #pragma unroll
  for(int m=0;m<4;m++){
    int e = (m*1024 + t)*8;
    int a = e >> 9, j = e & 511;
    *(bf16x8*)&t2s[a*520 + j] = ldb8(t2t + ((size_t)zc*64 + a)*LL + j);
  }
  float mfj[2];
  mfj[0] = mf[z*LL + jc0 + l15];
  mfj[1] = mf[z*LL + jc0 + 16 + l15];
  f32x4 mj[2][4];
  #pragma unroll
  for(int jt=0;jt<2;jt++)
    #pragma unroll
    for(int bt=0;bt<4;bt++) mj[jt][bt] = (f32x4){0.f,0.f,0.f,0.f};
  u16* PpTw = PpT + w*32*40;                    // wave-local transpose buffer

  for(int ip=0; ip<4; ++ip){
    int i0g = it*128 + ip*32;
    int par = ip & 1;
    f32x4 S[2][2];
    #pragma unroll
    for(int rt=0;rt<2;rt++){ S[rt][0] = (f32x4){0,0,0,0}; S[rt][1] = (f32x4){0,0,0,0}; }
    #pragma unroll
    for(int rt=0;rt<2;rt++){
      const u16* Ar = t1b + ((size_t)zc*LL + i0g + rt*16 + l15)*64 + lhi*8;
      bf16x8 a0 = ldb8(Ar), a1 = ldb8(Ar+32);
      #pragma unroll
      for(int ct=0;ct<2;ct++){
        const u16* Br = qzb + ((size_t)z*LL + jc0 + ct*16 + l15)*64 + lhi*8;
        S[rt][ct] = MFMA(a0, ldb8(Br), S[rt][ct]);
        S[rt][ct] = MFMA(a1, ldb8(Br+32), S[rt][ct]);
      }
    }
    #pragma unroll
    for(int rt=0;rt<2;rt++)
      #pragma unroll
      for(int jj=0;jj<4;jj++){
        int rloc = rt*16 + lhi*4 + jj;
        int irow = i0g + rloc;
        float mfi = mf[z*LL + irow];
        float ps = 0.f;
        #pragma unroll
        for(int ct=0;ct<2;ct++){
          int jcol = jc0 + ct*16 + l15;
          float v = S[rt][ct][jj] - ((irow==jcol)?BIGV:0.f);
          float e = mfi * mfj[ct] * __expf(v);
          S[rt][ct][jj] = e; ps += e;
          Pp[rloc*520 + jcol] = f2b(e);        // unnormalized
        }
        ps = g16_sum(ps);
        if(l15 == 0) atomicAdd(&redS2[par*32 + rloc], ps);   // ds_add_f32, no-return
      }
    __syncthreads();                            // B1: Pp + redS2[par] complete (t2s on ip=0)
    if(t < 32) redS2[(par^1)*32 + t] = 0.f;     // zero other parity for next panel
    float ivv[2][4];
    #pragma unroll
    for(int rt=0;rt<2;rt++)
      #pragma unroll
      for(int jj=0;jj<4;jj++){
        float s = redS2[par*32 + rt*16 + lhi*4 + jj];
        ivv[rt][jj] = s > 0.f ? 1.f/s : 0.f;
      }
    #pragma unroll
    for(int rt=0;rt<2;rt++)
      #pragma unroll
      for(int ct=0;ct<2;ct++){
        s16x4 v4 = { (short)f2b(S[rt][ct][0]*ivv[rt][0]), (short)f2b(S[rt][ct][1]*ivv[rt][1]),
                     (short)f2b(S[rt][ct][2]*ivv[rt][2]), (short)f2b(S[rt][ct][3]*ivv[rt][3]) };
        *(s16x4*)&PpTw[(ct*16 + l15)*40 + rt*16 + lhi*4] = v4;
      }
    {
      f32x4 mia = {0.f,0.f,0.f,0.f};
      const u16* Ab = Pp + (wr*16 + l15)*520 + h*256 + lhi*8;
      const u16* Bb = t2s + (wc*16 + l15)*520 + h*256 + lhi*8;
      #pragma unroll
      for(int ks=0;ks<8;ks++)
        mia = MFMA(ldb8(Ab + ks*32), ldb8(Bb + ks*32), mia);
      #pragma unroll
      for(int jj=0;jj<4;jj++)
        stgf[(h*32 + wr*16 + lhi*4 + jj)*68 + wc*16 + l15] = mia[jj]*ivv[wr][jj];
    }
    {
      bf16x8 av[2];
      #pragma unroll
      for(int jt=0;jt<2;jt++)
        av[jt] = ldb8(PpTw + (jt*16 + l15)*40 + lhi*8);
      #pragma unroll
      for(int bt=0;bt<4;bt++){
        bf16x8 b = ldb8(t1t + ((size_t)zc*64 + bt*16 + l15)*LL + i0g + lhi*8);
        #pragma unroll
        for(int jt=0;jt<2;jt++) mj[jt][bt] = MFMA(av[jt], b, mj[jt][bt]);
      }
    }
    __syncthreads();                            // B2: stgf ready; Pp/t2s reads done;
                                                //     orders parity-zero vs next atomics
    if(t < 512){
      int r = t>>4, cc = t&15;
      f32x4 v0 = *(const f32x4*)&stgf[r*68 + cc*4];
      f32x4 v1 = *(const f32x4*)&stgf[(32+r)*68 + cc*4];
      s16x4 o = { (short)f2b(v0[0]+v1[0]), (short)f2b(v0[1]+v1[1]),
                  (short)f2b(v0[2]+v1[2]), (short)f2b(v0[3]+v1[3]) };
      *(s16x4*)&miP[((size_t)z*LL + i0g + r)*512 + c*64 + cc*4] = o;
    }
  }
  // ---- mj dump: single pass, stg[512][72] reuses dead t2s+Pp space ----
  #pragma unroll
  for(int jt=0;jt<2;jt++)
    #pragma unroll
    for(int bt=0;bt<4;bt++)
      #pragma unroll
      for(int jj=0;jj<4;jj++)
        stg[(jc0 + jt*16 + lhi*4 + jj)*72 + bt*16 + l15] = f2b(mj[jt][bt][jj]);
  __syncthreads();
  #pragma unroll
  for(int q=0;q<4;q++){
    int e = q*1024 + t;
    int j = e >> 3, ch = e & 7;
    *(bf16x8*)&mjP[(((size_t)(it*8 + z))*LL + j)*512 + c*64 + ch*8]
      = *(const bf16x8*)&stg[j*72 + ch*8];
  }
}

extern "C" void kernel_launch(void* const* d_in, const int* in_sizes, int n_in,
                              void* d_out, int out_size, void* d_ws, size_t ws_size,
                              hipStream_t stream) {
  const float* x       = (const float*)d_in[0];
  const int*   mask    = (const int*)d_in[1];
  const float* ternary = (const float*)d_in[2];
  const float* gw      = (const float*)d_in[3];
  float* out = (float*)d_out;

  const size_t NE = (size_t)BB*LL*64;          // 262144
  char* p = (char*)d_ws;
  auto alloc = [&](size_t bytes)->void*{
    void* r = (void*)p; p += (bytes + 255) & ~(size_t)255; return r;
  };
  float* unary   = (float*)alloc(NE*4);
  float* mf      = (float*)alloc((size_t)BB*LL*4);
  u16*   qzb     = (u16*)alloc(NE*2);
  u16*   t1b     = (u16*)alloc((size_t)BB*HH*LL*64*2);   // 4.2 MB
  u16*   t1t     = (u16*)alloc((size_t)BB*HH*LL*64*2);   // 4.2 MB
  u16*   t2t     = (u16*)alloc((size_t)BB*HH*LL*64*2);   // 4.2 MB
  float* MgF     = (float*)alloc(NE*4);                  // 1 MB
  u16*   miP     = (u16*)alloc((size_t)BB*LL*512*2);     // 4.2 MB
  u16*   mjP     = (u16*)alloc((size_t)32*LL*512*2);     // 16.8 MB (4 it-partials)
  u16*   T4t     = (u16*)alloc(32768*2);
  u16*   Tt2     = (u16*)alloc(32768*2);
  u16*   Gt      = (u16*)alloc(4096*2);
  u16*   Gt2     = (u16*)alloc(4096*2);

  const int KF_LDS = 158464;  // t2s + Pp + PpT + redS2 + stgf
  hipFuncSetAttribute(reinterpret_cast<const void*>(kF),
                      hipFuncAttributeMaxDynamicSharedMemorySize, KF_LDS);

  kp_prep<<<128, 256, 0, stream>>>(ternary, gw, T4t, Tt2, Gt, Gt2);
  kCA<<<256, 512, 0, stream>>>(x, mask, miP, mjP, MgF, unary, mf, Gt2, Gt,
                               T4t, Tt2, qzb, MgF, out, t1b, t1t, t2t, 0);
  for(int it=0; it<4; ++it){
    kF<<<256, 1024, KF_LDS, stream>>>(t1b, qzb, t1t, t2t, mf, miP, mjP);
    kCA<<<256, 512, 0, stream>>>(x, mask, miP, mjP, MgF, unary, mf, Gt2, Gt,
                                 T4t, Tt2, qzb, MgF, out, t1b, t1t, t2t, (it==3) ? 2 : 1);
  }
}